// Round 7
// baseline (425.979 us; speedup 1.0000x reference)
//
#include <hip/hip_runtime.h>

// GraphSAGE forward, SPLIT architecture (round 7):
//   CSR build -> per level: [pure gather kernel -> pure MLP kernel] -> k_out.
//
// Proven invariants kept:
//  - Gather: GSIZE lanes/node read ONE full contiguous row per vmem instr
//    (float4); indices prefetched lane-parallel + shfl broadcast; 4-unroll.
//  - Stores: contiguous rows of consecutive nodes per instruction.
//  - Algebra: mean_agg(h)@W == mean_agg(h@W). L3 emits g=h3@Wa4; L4 skips Wa.
//    L1 keeps raw gather (600KB L2-resident) and folds Wa1 into its MLP.
// New: gather kernels have ZERO LDS/barriers -> 32 waves/CU for latency
// hiding; MLP kernels are register-tiled (NR=2 x float4 per thread) with a
// single 16KB weight LDS buffer reloaded per stage (3 blocks/CU).

__global__ __launch_bounds__(256) void k_count(const int* __restrict__ edst,
                                               int* __restrict__ deg, int E) {
    int t = blockIdx.x * blockDim.x + threadIdx.x;
    if (t < E) atomicAdd(&deg[edst[t]], 1);
}

__global__ __launch_bounds__(256) void k_blocksum(const int* __restrict__ deg,
                                                  int* __restrict__ bsums, int N) {
    __shared__ int s[256];
    int t = threadIdx.x;
    int base = blockIdx.x * 1024 + t * 4;
    int v = 0;
#pragma unroll
    for (int j = 0; j < 4; j++) { int idx = base + j; if (idx < N) v += deg[idx]; }
    s[t] = v; __syncthreads();
    for (int o = 128; o > 0; o >>= 1) { if (t < o) s[t] += s[t + o]; __syncthreads(); }
    if (t == 0) bsums[blockIdx.x] = s[0];
}

__global__ __launch_bounds__(256) void k_scantop(int* __restrict__ bsums, int NB) {
    __shared__ int s[256];
    int t = threadIdx.x;
    int v = (t < NB) ? bsums[t] : 0;
    s[t] = v; __syncthreads();
    for (int o = 1; o < 256; o <<= 1) {
        int x = (t >= o) ? s[t - o] : 0;
        __syncthreads();
        s[t] += x;
        __syncthreads();
    }
    if (t < NB) bsums[t] = s[t] - v;
}

__global__ __launch_bounds__(256) void k_scanfinal(const int* __restrict__ deg,
                                                   const int* __restrict__ bsums,
                                                   int* __restrict__ offsets,
                                                   int* __restrict__ cursor,
                                                   float* __restrict__ inv_cnt,
                                                   int N, int E) {
    __shared__ int s[256];
    int t = threadIdx.x, b = blockIdx.x;
    int base = b * 1024 + t * 4;
    int d[4]; int lsum = 0;
#pragma unroll
    for (int j = 0; j < 4; j++) { int idx = base + j; d[j] = (idx < N) ? deg[idx] : 0; lsum += d[j]; }
    s[t] = lsum; __syncthreads();
    for (int o = 1; o < 256; o <<= 1) {
        int x = (t >= o) ? s[t - o] : 0;
        __syncthreads();
        s[t] += x;
        __syncthreads();
    }
    int p = bsums[b] + s[t] - lsum;
#pragma unroll
    for (int j = 0; j < 4; j++) {
        int idx = base + j;
        if (idx < N) {
            offsets[idx] = p;
            cursor[idx] = p;
            inv_cnt[idx] = 1.0f / (float)(d[j] > 0 ? d[j] : 1);
            p += d[j];
        }
    }
    if (b == 0 && t == 0) offsets[N] = E;
}

__global__ __launch_bounds__(256) void k_scatter(const int* __restrict__ esrc,
                                                 const int* __restrict__ edst,
                                                 int* __restrict__ cursor,
                                                 int* __restrict__ csr, int E) {
    int t = blockIdx.x * blockDim.x + threadIdx.x;
    if (t < E) {
        int d = edst[t];
        int pos = atomicAdd(&cursor[d], 1);
        csr[pos] = esrc[t];
    }
}

// ---------------- pure gather kernels (no LDS, no barriers) ----------------

// Row = GSIZE float4s; GSIZE lanes per node, each owns one float4 of the row.
template <int GSIZE>
__global__ __launch_bounds__(256, 8) void k_gather(
    const float* __restrict__ hin, float* __restrict__ mout,
    const int* __restrict__ offsets, const int* __restrict__ csr,
    const float* __restrict__ inv_cnt, int N) {
    constexpr int NPG = 64 / GSIZE;
    constexpr int NPB = 4 * NPG;
    const int t = threadIdx.x, lane = t & 63, wid = t >> 6;
    const int g = lane / GSIZE, lg = lane % GSIZE;
    const int srcb = g * GSIZE;
    const int node = blockIdx.x * NPB + wid * NPG + g;
    if (node >= N) return;

    const float4* hp = (const float4*)hin;
    int start = offsets[node], end = offsets[node + 1];
    float4 acc = make_float4(0.f, 0.f, 0.f, 0.f);
    for (int bb = start; bb < end; bb += GSIZE) {
        int cnt = min(GSIZE, end - bb);
        int sidx = (lg < cnt) ? csr[bb + lg] : 0;
        int i = 0;
        for (; i + 4 <= cnt; i += 4) {
            int s0 = __shfl(sidx, srcb + i);
            int s1 = __shfl(sidx, srcb + i + 1);
            int s2 = __shfl(sidx, srcb + i + 2);
            int s3 = __shfl(sidx, srcb + i + 3);
            float4 v0 = hp[(size_t)s0 * GSIZE + lg];
            float4 v1 = hp[(size_t)s1 * GSIZE + lg];
            float4 v2 = hp[(size_t)s2 * GSIZE + lg];
            float4 v3 = hp[(size_t)s3 * GSIZE + lg];
            acc.x += (v0.x + v1.x) + (v2.x + v3.x);
            acc.y += (v0.y + v1.y) + (v2.y + v3.y);
            acc.z += (v0.z + v1.z) + (v2.z + v3.z);
            acc.w += (v0.w + v1.w) + (v2.w + v3.w);
        }
        for (; i < cnt; ++i) {
            int s0 = __shfl(sidx, srcb + i);
            float4 v0 = hp[(size_t)s0 * GSIZE + lg];
            acc.x += v0.x; acc.y += v0.y; acc.z += v0.z; acc.w += v0.w;
        }
    }
    float ic = inv_cnt[node];
    acc.x *= ic; acc.y *= ic; acc.z *= ic; acc.w *= ic;
    ((float4*)mout)[(size_t)node * GSIZE + lg] = acc;
}

// Raw features: 3 floats/row, 600KB array (L2-resident). 4 lanes/node, lg<3 load.
__global__ __launch_bounds__(256, 8) void k_gather3(
    const float* __restrict__ raw, float* __restrict__ m0,
    const int* __restrict__ offsets, const int* __restrict__ csr,
    const float* __restrict__ inv_cnt, int N) {
    constexpr int GSIZE = 4, NPG = 16, NPB = 64;
    const int t = threadIdx.x, lane = t & 63, wid = t >> 6;
    const int g = lane / GSIZE, lg = lane % GSIZE;
    const int srcb = g * GSIZE;
    const int node = blockIdx.x * NPB + wid * NPG + g;
    if (node >= N) return;

    int start = offsets[node], end = offsets[node + 1];
    float acc = 0.f;
    for (int bb = start; bb < end; bb += GSIZE) {
        int cnt = min(GSIZE, end - bb);
        int sidx = (lg < cnt) ? csr[bb + lg] : 0;
        int i = 0;
        for (; i + 4 <= cnt; i += 4) {
            int s0 = __shfl(sidx, srcb + i);
            int s1 = __shfl(sidx, srcb + i + 1);
            int s2 = __shfl(sidx, srcb + i + 2);
            int s3 = __shfl(sidx, srcb + i + 3);
            if (lg < 3) {
                acc += raw[(size_t)s0 * 3 + lg] + raw[(size_t)s1 * 3 + lg]
                     + raw[(size_t)s2 * 3 + lg] + raw[(size_t)s3 * 3 + lg];
            }
        }
        for (; i < cnt; ++i) {
            int s0 = __shfl(sidx, srcb + i);
            if (lg < 3) acc += raw[(size_t)s0 * 3 + lg];
        }
    }
    if (lg < 3) m0[(size_t)node * 4 + lg] = acc * inv_cnt[node];
}

// ---------------- MLP kernels (register-tiled chained GEMMs) ----------------

template <int NT, int PAD, int K, int D, bool RIN, bool ROUT, int NR>
__device__ inline void mlp_stage_lds(const float* sIn, const float* sW,
                                     float* sOut, int t) {
    constexpr int CQ = D / 4;
    constexpr int TILES = (NT / NR) * CQ;
    static_assert(TILES <= 512, "tile overflow");
    if (t < TILES) {
        int rb = t / CQ, q = t % CQ;
        float acc[NR][4] = {};
#pragma unroll
        for (int k = 0; k < K; ++k) {
            float4 w = *(const float4*)&sW[k * D + 4 * q];
#pragma unroll
            for (int jr = 0; jr < NR; ++jr) {
                float mv = sIn[(rb * NR + jr) * PAD + k];
                if constexpr (RIN) mv = fmaxf(mv, 0.f);
                acc[jr][0] += mv * w.x; acc[jr][1] += mv * w.y;
                acc[jr][2] += mv * w.z; acc[jr][3] += mv * w.w;
            }
        }
#pragma unroll
        for (int jr = 0; jr < NR; ++jr) {
            float4 r;
            r.x = ROUT ? fmaxf(acc[jr][0], 0.f) : acc[jr][0];
            r.y = ROUT ? fmaxf(acc[jr][1], 0.f) : acc[jr][1];
            r.z = ROUT ? fmaxf(acc[jr][2], 0.f) : acc[jr][2];
            r.w = ROUT ? fmaxf(acc[jr][3], 0.f) : acc[jr][3];
            *(float4*)&sOut[(rb * NR + jr) * PAD + 4 * q] = r;
        }
    }
}

template <int NT, int PAD, int K, int D, bool RIN, bool ROUT, int NR>
__device__ inline void mlp_stage_out(const float* sIn, const float* sW,
                                     float* __restrict__ dst, int base, int N, int t) {
    constexpr int CQ = D / 4;
    constexpr int TILES = (NT / NR) * CQ;
    static_assert(TILES <= 512, "tile overflow");
    if (t < TILES) {
        int rb = t / CQ, q = t % CQ;
        float acc[NR][4] = {};
#pragma unroll
        for (int k = 0; k < K; ++k) {
            float4 w = *(const float4*)&sW[k * D + 4 * q];
#pragma unroll
            for (int jr = 0; jr < NR; ++jr) {
                float mv = sIn[(rb * NR + jr) * PAD + k];
                if constexpr (RIN) mv = fmaxf(mv, 0.f);
                acc[jr][0] += mv * w.x; acc[jr][1] += mv * w.y;
                acc[jr][2] += mv * w.z; acc[jr][3] += mv * w.w;
            }
        }
#pragma unroll
        for (int jr = 0; jr < NR; ++jr) {
            int node = base + rb * NR + jr;
            if (node < N) {
                float4 r;
                r.x = ROUT ? fmaxf(acc[jr][0], 0.f) : acc[jr][0];
                r.y = ROUT ? fmaxf(acc[jr][1], 0.f) : acc[jr][1];
                r.z = ROUT ? fmaxf(acc[jr][2], 0.f) : acc[jr][2];
                r.w = ROUT ? fmaxf(acc[jr][3], 0.f) : acc[jr][3];
                *(float4*)&dst[(size_t)node * D + 4 * q] = r;
            }
        }
    }
}

// Chained per-node-tile MLP: stage1 (K1->D1), opt stage2 (K2->D2), opt stage3.
// K1P = physical float stride of the input rows (>=K1, multiple of 4).
template <int NT, int K1P, int K1, int D1, bool RIN1, int K2, int D2,
          int K3, int D3, bool ROUT_LAST>
__global__ __launch_bounds__(512, 4) void k_mlp(
    const float* __restrict__ min_, float* __restrict__ out_,
    const float* __restrict__ W1, const float* __restrict__ W2,
    const float* __restrict__ W3, int N) {
    constexpr int PAD = 68;
    __shared__ alignas(16) float sW[4096];
    __shared__ alignas(16) float sX[NT * PAD];
    __shared__ alignas(16) float sY[NT * PAD];
    const int t = threadIdx.x;
    const int base = blockIdx.x * NT;

    constexpr int RQ = K1P / 4;
    for (int idx = t; idx < NT * RQ; idx += 512) {
        int row = idx / RQ, q = idx % RQ;
        int node = base + row;
        float4 v = (node < N) ? ((const float4*)min_)[(size_t)node * RQ + q]
                              : make_float4(0.f, 0.f, 0.f, 0.f);
        *(float4*)&sX[row * PAD + 4 * q] = v;
    }
    for (int i = t; i < K1 * D1; i += 512) sW[i] = W1[i];
    __syncthreads();

    if constexpr (K2 == 0) {
        mlp_stage_out<NT, PAD, K1, D1, RIN1, ROUT_LAST, 2>(sX, sW, out_, base, N, t);
    } else {
        mlp_stage_lds<NT, PAD, K1, D1, RIN1, true, 2>(sX, sW, sY, t);
        __syncthreads();
        for (int i = t; i < K2 * D2; i += 512) sW[i] = W2[i];
        __syncthreads();
        if constexpr (K3 == 0) {
            mlp_stage_out<NT, PAD, K2, D2, false, ROUT_LAST, 2>(sY, sW, out_, base, N, t);
        } else {
            mlp_stage_lds<NT, PAD, K2, D2, false, true, 2>(sY, sW, sX, t);
            __syncthreads();
            for (int i = t; i < K3 * D3; i += 512) sW[i] = W3[i];
            __syncthreads();
            mlp_stage_out<NT, PAD, K3, D3, false, ROUT_LAST, 2>(sX, sW, out_, base, N, t);
        }
    }
}

// ---------------- output projection (staged) ----------------

__global__ __launch_bounds__(256, 8) void k_out(const float* __restrict__ h,
                                                const int* __restrict__ nodes,
                                                const float* __restrict__ Wout,
                                                float* __restrict__ out, int B) {
    __shared__ alignas(16) float sH[32][36];
    __shared__ float sW[32 * 40];
    __shared__ int sIdx[32];
    const int t = threadIdx.x;
    const int base = blockIdx.x * 32;
    if (t < 32) sIdx[t] = (base + t < B) ? nodes[base + t] : 0;
    for (int i = t; i < 32 * 40; i += 256) sW[i] = Wout[i];
    __syncthreads();
    {
        int g = t >> 3, lg = t & 7;  // 32 groups x 8 lanes: one 128B row each
        *(float4*)&sH[g][4 * lg] = ((const float4*)h)[(size_t)sIdx[g] * 8 + lg];
    }
    __syncthreads();
#pragma unroll
    for (int j = 0; j < 5; ++j) {
        int idx = t + j * 256;           // 32*40 = 1280 outputs
        int n = idx / 40, c = idx % 40;
        if (base + n < B) {
            float s = 0.f;
#pragma unroll
            for (int k = 0; k < 32; ++k) s += sH[n][k] * sW[k * 40 + c];
            out[(size_t)(base + n) * 40 + c] = s;
        }
    }
}

extern "C" void kernel_launch(void* const* d_in, const int* in_sizes, int n_in,
                              void* d_out, int out_size, void* d_ws, size_t ws_size,
                              hipStream_t stream) {
    const float* raw  = (const float*)d_in[0];
    const int* nodes  = (const int*)d_in[1];
    const int* esrc   = (const int*)d_in[2];
    const int* edst   = (const int*)d_in[3];
    const float* Wa1 = (const float*)d_in[4];
    const float* Wa2 = (const float*)d_in[5];
    const float* Wa3 = (const float*)d_in[6];
    const float* Wa4 = (const float*)d_in[7];
    const float* We1 = (const float*)d_in[8];
    const float* We2 = (const float*)d_in[9];
    const float* We3 = (const float*)d_in[10];
    const float* We4 = (const float*)d_in[11];
    const float* Wout = (const float*)d_in[12];
    float* out = (float*)d_out;

    int N = in_sizes[1];   // 50000
    int E = in_sizes[2];   // 850000
    int B = N;

    char* p = (char*)d_ws;
    auto alloc = [&](size_t bytes) -> char* {
        char* r = p;
        p += (bytes + 255) & ~(size_t)255;
        return r;
    };
    int*   deg     = (int*)alloc((size_t)N * 4);
    int*   offsets = (int*)alloc((size_t)(N + 1) * 4);
    int*   cursor  = (int*)alloc((size_t)N * 4);
    float* inv_cnt = (float*)alloc((size_t)N * 4);
    int NB = (N + 1023) / 1024;
    int*   bsums   = (int*)alloc((size_t)NB * 4);
    int*   csr     = (int*)alloc((size_t)E * 4);
    float* bufA    = (float*)alloc((size_t)N * 64 * 4);  // 12.8MB
    float* bufB    = (float*)alloc((size_t)N * 64 * 4);  // 12.8MB
    float* bufC    = (float*)alloc((size_t)N * 32 * 4);  // 6.4MB
    (void)ws_size; (void)n_in; (void)out_size;

    hipMemsetAsync(deg, 0, (size_t)N * 4, stream);
    int eb = (E + 255) / 256;
    k_count<<<eb, 256, 0, stream>>>(edst, deg, E);
    k_blocksum<<<NB, 256, 0, stream>>>(deg, bsums, N);
    k_scantop<<<1, 256, 0, stream>>>(bsums, NB);
    k_scanfinal<<<NB, 256, 0, stream>>>(deg, bsums, offsets, cursor, inv_cnt, N, E);
    k_scatter<<<eb, 256, 0, stream>>>(esrc, edst, cursor, csr, E);

    auto cdiv = [](int a, int b) { return (a + b - 1) / b; };
    float* m0 = bufC;  // [N x 4]  (col 3 unused)
    float* h1 = bufA;  // [N x 32]
    float* m1 = bufC;  // [N x 32]
    float* h2 = bufB;  // [N x 64]
    float* m2 = bufA;  // [N x 64]
    float* g_ = bufC;  // [N x 32]
    float* m3 = bufB;  // [N x 32]
    float* h4 = bufC;  // [N x 32]

    // L1: m0 = mean(raw); h1 = relu(relu(m0@Wa1)@We1)
    k_gather3<<<cdiv(N, 64), 256, 0, stream>>>(raw, m0, offsets, csr, inv_cnt, N);
    k_mlp<64, 4, 3, 32, false, 32, 32, 0, 0, true>
        <<<cdiv(N, 64), 512, 0, stream>>>(m0, h1, Wa1, We1, nullptr, N);
    // L2
    k_gather<8><<<cdiv(N, 32), 256, 0, stream>>>(h1, m1, offsets, csr, inv_cnt, N);
    k_mlp<64, 32, 32, 32, false, 32, 64, 0, 0, true>
        <<<cdiv(N, 64), 512, 0, stream>>>(m1, h2, Wa2, We2, nullptr, N);
    // L3 (+ fold Wa4: g = h3@Wa4, no relu)
    k_gather<16><<<cdiv(N, 16), 256, 0, stream>>>(h2, m2, offsets, csr, inv_cnt, N);
    k_mlp<64, 64, 64, 64, false, 64, 64, 64, 32, false>
        <<<cdiv(N, 64), 512, 0, stream>>>(m2, g_, Wa3, We3, Wa4, N);
    // L4: a = relu(mean(g)); h4 = relu(a@We4)
    k_gather<8><<<cdiv(N, 32), 256, 0, stream>>>(g_, m3, offsets, csr, inv_cnt, N);
    k_mlp<64, 32, 32, 32, true, 0, 0, 0, 0, true>
        <<<cdiv(N, 64), 512, 0, stream>>>(m3, h4, We4, nullptr, nullptr, N);

    k_out<<<cdiv(B, 32), 256, 0, stream>>>(h4, nodes, Wout, out, B);
}

// Round 8
// 251.984 us; speedup vs baseline: 1.6905x; 1.6905x over previous
//
#include <hip/hip_runtime.h>

// GraphSAGE forward — round 8: consolidate on the round-2 champion structure
// (fused gather+GEMM k_level, wave-private LDS slots, no inner barriers,
// float2 full-contiguous-row gathers, moderate occupancy) plus the algebraic
// fold g = h3 @ Wa4 done by a tiny dense kernel so L4 gathers 128B rows and
// skips its Wa GEMM.
//
// Hard-won invariants:
//  - Gather must read ONE full contiguous row per vmem instruction, with
//    indices shfl-broadcast (r3/r4 fragmentation: FETCH 199-636MB).
//  - Gather concurrency must stay moderate & fused with compute: a dedicated
//    32-wave/CU gather kernel doubles HBM traffic (r7: 80->160MB FETCH).
//  - mean_agg(h)@W == mean_agg(h@W) (fold verified r5-r7).

__global__ __launch_bounds__(256) void k_count(const int* __restrict__ edst,
                                               int* __restrict__ deg, int E) {
    int t = blockIdx.x * blockDim.x + threadIdx.x;
    if (t < E) atomicAdd(&deg[edst[t]], 1);
}

__global__ __launch_bounds__(256) void k_blocksum(const int* __restrict__ deg,
                                                  int* __restrict__ bsums, int N) {
    __shared__ int s[256];
    int t = threadIdx.x;
    int base = blockIdx.x * 1024 + t * 4;
    int v = 0;
#pragma unroll
    for (int j = 0; j < 4; j++) { int idx = base + j; if (idx < N) v += deg[idx]; }
    s[t] = v; __syncthreads();
    for (int o = 128; o > 0; o >>= 1) { if (t < o) s[t] += s[t + o]; __syncthreads(); }
    if (t == 0) bsums[blockIdx.x] = s[0];
}

__global__ __launch_bounds__(256) void k_scantop(int* __restrict__ bsums, int NB) {
    __shared__ int s[256];
    int t = threadIdx.x;
    int v = (t < NB) ? bsums[t] : 0;
    s[t] = v; __syncthreads();
    for (int o = 1; o < 256; o <<= 1) {
        int x = (t >= o) ? s[t - o] : 0;
        __syncthreads();
        s[t] += x;
        __syncthreads();
    }
    if (t < NB) bsums[t] = s[t] - v;
}

__global__ __launch_bounds__(256) void k_scanfinal(const int* __restrict__ deg,
                                                   const int* __restrict__ bsums,
                                                   int* __restrict__ offsets,
                                                   int* __restrict__ cursor,
                                                   float* __restrict__ inv_cnt,
                                                   int N, int E) {
    __shared__ int s[256];
    int t = threadIdx.x, b = blockIdx.x;
    int base = b * 1024 + t * 4;
    int d[4]; int lsum = 0;
#pragma unroll
    for (int j = 0; j < 4; j++) { int idx = base + j; d[j] = (idx < N) ? deg[idx] : 0; lsum += d[j]; }
    s[t] = lsum; __syncthreads();
    for (int o = 1; o < 256; o <<= 1) {
        int x = (t >= o) ? s[t - o] : 0;
        __syncthreads();
        s[t] += x;
        __syncthreads();
    }
    int p = bsums[b] + s[t] - lsum;
#pragma unroll
    for (int j = 0; j < 4; j++) {
        int idx = base + j;
        if (idx < N) {
            offsets[idx] = p;
            cursor[idx] = p;
            inv_cnt[idx] = 1.0f / (float)(d[j] > 0 ? d[j] : 1);
            p += d[j];
        }
    }
    if (b == 0 && t == 0) offsets[N] = E;
}

__global__ __launch_bounds__(256) void k_scatter(const int* __restrict__ esrc,
                                                 const int* __restrict__ edst,
                                                 int* __restrict__ cursor,
                                                 int* __restrict__ csr, int E) {
    int t = blockIdx.x * blockDim.x + threadIdx.x;
    if (t < E) {
        int d = edst[t];
        int pos = atomicAdd(&cursor[d], 1);
        csr[pos] = esrc[t];
    }
}

// ---- round-2 proven fused level body (wave-private slots, no inner barriers) ----
template <int DIN, int DMID, int DOUT, int GSIZE, bool HAS_WA>
__device__ __forceinline__ void level_body(
    const float* __restrict__ hprev, float* __restrict__ hnext,
    const int* __restrict__ offsets, const int* __restrict__ csr,
    const float* __restrict__ inv_cnt,
    const float* __restrict__ Wa, const float* __restrict__ We, int N) {
    constexpr int WAVES = 8;
    constexpr int NPG = 64 / GSIZE;   // nodes per wave
    constexpr int NPB = WAVES * NPG;  // nodes per block
    constexpr bool V2 = (DIN == 2 * GSIZE);

    __shared__ float sWa[HAS_WA ? DIN * DMID : 1];
    __shared__ float sWe[DMID * DOUT];
    __shared__ float sM[NPB * DIN];   // wave-private slots
    __shared__ float sA[NPB * DMID];  // wave-private slots

    if constexpr (HAS_WA)
        for (int i = threadIdx.x; i < DIN * DMID; i += 512) sWa[i] = Wa[i];
    for (int i = threadIdx.x; i < DMID * DOUT; i += 512) sWe[i] = We[i];
    __syncthreads();

    const int lane = threadIdx.x & 63;
    const int wid  = threadIdx.x >> 6;
    const int g    = lane / GSIZE;
    const int lg   = lane & (GSIZE - 1);
    const int slot = wid * NPG + g;
    const int srcb = g * GSIZE;
    const long stride = (long)gridDim.x * NPB;

    for (long base = (long)blockIdx.x * NPB; base < N; base += stride) {
        int node = (int)base + slot;
        if (node < N) {
            int start = offsets[node], end = offsets[node + 1];
            float m0 = 0, m1 = 0, n0 = 0, n1 = 0, p0 = 0, p1 = 0, q0 = 0, q1 = 0;
            for (int bb = start; bb < end; bb += GSIZE) {
                int cnt = min(GSIZE, end - bb);
                int sidx = (lg < cnt) ? csr[bb + lg] : 0;
                int i = 0;
                for (; i + 4 <= cnt; i += 4) {
                    int s0 = __shfl(sidx, srcb + i);
                    int s1 = __shfl(sidx, srcb + i + 1);
                    int s2 = __shfl(sidx, srcb + i + 2);
                    int s3 = __shfl(sidx, srcb + i + 3);
                    if (V2) {
                        const float2* hp = (const float2*)hprev;
                        float2 v0 = hp[(size_t)s0 * (DIN / 2) + lg];
                        float2 v1 = hp[(size_t)s1 * (DIN / 2) + lg];
                        float2 v2 = hp[(size_t)s2 * (DIN / 2) + lg];
                        float2 v3 = hp[(size_t)s3 * (DIN / 2) + lg];
                        m0 += v0.x; m1 += v0.y;
                        n0 += v1.x; n1 += v1.y;
                        p0 += v2.x; p1 += v2.y;
                        q0 += v3.x; q1 += v3.y;
                    } else if (lg < DIN) {
                        m0 += hprev[(size_t)s0 * DIN + lg];
                        n0 += hprev[(size_t)s1 * DIN + lg];
                        p0 += hprev[(size_t)s2 * DIN + lg];
                        q0 += hprev[(size_t)s3 * DIN + lg];
                    }
                }
                for (; i < cnt; ++i) {
                    int s0 = __shfl(sidx, srcb + i);
                    if (V2) {
                        const float2* hp = (const float2*)hprev;
                        float2 v0 = hp[(size_t)s0 * (DIN / 2) + lg];
                        m0 += v0.x; m1 += v0.y;
                    } else if (lg < DIN) {
                        m0 += hprev[(size_t)s0 * DIN + lg];
                    }
                }
            }
            float ic = inv_cnt[node];
            float fx = ((m0 + n0) + (p0 + q0)) * ic;
            if (V2) {
                float fy = ((m1 + n1) + (p1 + q1)) * ic;
                sM[slot * DIN + 2 * lg]     = fx;
                sM[slot * DIN + 2 * lg + 1] = fy;
            } else if (lg < DIN) {
                sM[slot * DIN + lg] = fx;
            }
        }
        // a = relu(m @ Wa)  (or a = relu(m) when Wa is folded upstream)
        constexpr int AO = NPG * DMID;
#pragma unroll
        for (int r = 0; r < AO / 64; ++r) {
            int oi = r * 64 + lane;
            int sl = wid * NPG + oi / DMID;
            int col = oi & (DMID - 1);
            if ((int)base + sl < N) {
                if constexpr (HAS_WA) {
                    float v = 0.f;
#pragma unroll
                    for (int k = 0; k < DIN; ++k) v += sM[sl * DIN + k] * sWa[k * DMID + col];
                    sA[sl * DMID + col] = fmaxf(v, 0.f);
                } else {
                    sA[sl * DMID + col] = fmaxf(sM[sl * DIN + col], 0.f);
                }
            }
        }
        // h = relu(a @ We)
        constexpr int HO = NPG * DOUT;
#pragma unroll
        for (int r = 0; r < HO / 64; ++r) {
            int oi = r * 64 + lane;
            int sl = wid * NPG + oi / DOUT;
            int col = oi & (DOUT - 1);
            int nd = (int)base + sl;
            if (nd < N) {
                float v = 0.f;
#pragma unroll
                for (int k = 0; k < DMID; ++k) v += sA[sl * DMID + k] * sWe[k * DOUT + col];
                hnext[(size_t)nd * DOUT + col] = fmaxf(v, 0.f);
            }
        }
    }
}

// Distinctly-named wrappers for clean rocprof attribution.
__global__ __launch_bounds__(512, 8) void k_lvl1(
    const float* __restrict__ hprev, float* __restrict__ hnext,
    const int* __restrict__ offsets, const int* __restrict__ csr,
    const float* __restrict__ inv_cnt, const float* __restrict__ Wa,
    const float* __restrict__ We, int N) {
    level_body<3, 32, 32, 4, true>(hprev, hnext, offsets, csr, inv_cnt, Wa, We, N);
}
__global__ __launch_bounds__(512, 8) void k_lvl2(
    const float* __restrict__ hprev, float* __restrict__ hnext,
    const int* __restrict__ offsets, const int* __restrict__ csr,
    const float* __restrict__ inv_cnt, const float* __restrict__ Wa,
    const float* __restrict__ We, int N) {
    level_body<32, 32, 64, 16, true>(hprev, hnext, offsets, csr, inv_cnt, Wa, We, N);
}
__global__ __launch_bounds__(512, 8) void k_lvl3(
    const float* __restrict__ hprev, float* __restrict__ hnext,
    const int* __restrict__ offsets, const int* __restrict__ csr,
    const float* __restrict__ inv_cnt, const float* __restrict__ Wa,
    const float* __restrict__ We, int N) {
    level_body<64, 64, 64, 32, true>(hprev, hnext, offsets, csr, inv_cnt, Wa, We, N);
}
__global__ __launch_bounds__(512, 8) void k_lvl4(
    const float* __restrict__ hprev, float* __restrict__ hnext,
    const int* __restrict__ offsets, const int* __restrict__ csr,
    const float* __restrict__ inv_cnt, const float* __restrict__ Wa,
    const float* __restrict__ We, int N) {
    level_body<32, 32, 32, 16, false>(hprev, hnext, offsets, csr, inv_cnt, Wa, We, N);
}

// Dense fold: g[N x 32] = h3[N x 64] @ Wa4[64 x 32]  (no relu).
__global__ __launch_bounds__(256) void k_fold(const float* __restrict__ h3,
                                              const float* __restrict__ Wg,
                                              float* __restrict__ g, int N) {
    __shared__ float sW[64 * 32];
    __shared__ float sH[32 * 68];
    const int t = threadIdx.x;
    const int base = blockIdx.x * 32;
    for (int i = t; i < 64 * 32; i += 256) sW[i] = Wg[i];
    for (int idx = t; idx < 512; idx += 256) {
        int row = idx >> 4, q = idx & 15;
        int node = base + row;
        float4 v = (node < N) ? ((const float4*)h3)[(size_t)node * 16 + q]
                              : make_float4(0.f, 0.f, 0.f, 0.f);
        *(float4*)&sH[row * 68 + 4 * q] = v;
    }
    __syncthreads();
    const int row = t >> 3, q = t & 7;
    const int node = base + row;
    if (node < N) {
        float ax = 0.f, ay = 0.f, az = 0.f, aw = 0.f;
#pragma unroll
        for (int k = 0; k < 64; ++k) {
            float mv = sH[row * 68 + k];
            const float* w = &sW[k * 32 + 4 * q];
            ax += mv * w[0]; ay += mv * w[1]; az += mv * w[2]; aw += mv * w[3];
        }
        float4 r = make_float4(ax, ay, az, aw);
        ((float4*)g)[(size_t)node * 8 + q] = r;
    }
}

// Staged output projection (proven r7): rows via LDS, cooperative 40-col outputs.
__global__ __launch_bounds__(256, 8) void k_out(const float* __restrict__ h,
                                                const int* __restrict__ nodes,
                                                const float* __restrict__ Wout,
                                                float* __restrict__ out, int B) {
    __shared__ alignas(16) float sH[32][36];
    __shared__ float sW[32 * 40];
    __shared__ int sIdx[32];
    const int t = threadIdx.x;
    const int base = blockIdx.x * 32;
    if (t < 32) sIdx[t] = (base + t < B) ? nodes[base + t] : 0;
    for (int i = t; i < 32 * 40; i += 256) sW[i] = Wout[i];
    __syncthreads();
    {
        int g = t >> 3, lg = t & 7;
        *(float4*)&sH[g][4 * lg] = ((const float4*)h)[(size_t)sIdx[g] * 8 + lg];
    }
    __syncthreads();
#pragma unroll
    for (int j = 0; j < 5; ++j) {
        int idx = t + j * 256;  // 32*40 = 1280 outputs
        int n = idx / 40, c = idx % 40;
        if (base + n < B) {
            float s = 0.f;
#pragma unroll
            for (int k = 0; k < 32; ++k) s += sH[n][k] * sW[k * 40 + c];
            out[(size_t)(base + n) * 40 + c] = s;
        }
    }
}

extern "C" void kernel_launch(void* const* d_in, const int* in_sizes, int n_in,
                              void* d_out, int out_size, void* d_ws, size_t ws_size,
                              hipStream_t stream) {
    const float* raw  = (const float*)d_in[0];
    const int* nodes  = (const int*)d_in[1];
    const int* esrc   = (const int*)d_in[2];
    const int* edst   = (const int*)d_in[3];
    const float* Wa1 = (const float*)d_in[4];
    const float* Wa2 = (const float*)d_in[5];
    const float* Wa3 = (const float*)d_in[6];
    const float* Wa4 = (const float*)d_in[7];
    const float* We1 = (const float*)d_in[8];
    const float* We2 = (const float*)d_in[9];
    const float* We3 = (const float*)d_in[10];
    const float* We4 = (const float*)d_in[11];
    const float* Wout = (const float*)d_in[12];
    float* out = (float*)d_out;

    int N = in_sizes[1];   // 50000
    int E = in_sizes[2];   // 850000
    int B = N;

    char* p = (char*)d_ws;
    auto alloc = [&](size_t bytes) -> char* {
        char* r = p;
        p += (bytes + 255) & ~(size_t)255;
        return r;
    };
    int*   deg     = (int*)alloc((size_t)N * 4);
    int*   offsets = (int*)alloc((size_t)(N + 1) * 4);
    int*   cursor  = (int*)alloc((size_t)N * 4);
    float* inv_cnt = (float*)alloc((size_t)N * 4);
    int NB = (N + 1023) / 1024;
    int*   bsums   = (int*)alloc((size_t)NB * 4);
    int*   csr     = (int*)alloc((size_t)E * 4);
    float* bufA    = (float*)alloc((size_t)N * 64 * 4);
    float* bufB    = (float*)alloc((size_t)N * 64 * 4);
    float* bufC    = (float*)alloc((size_t)N * 32 * 4);
    (void)ws_size; (void)n_in; (void)out_size;

    hipMemsetAsync(deg, 0, (size_t)N * 4, stream);
    int eb = (E + 255) / 256;
    k_count<<<eb, 256, 0, stream>>>(edst, deg, E);
    k_blocksum<<<NB, 256, 0, stream>>>(deg, bsums, N);
    k_scantop<<<1, 256, 0, stream>>>(bsums, NB);
    k_scanfinal<<<NB, 256, 0, stream>>>(deg, bsums, offsets, cursor, inv_cnt, N, E);
    k_scatter<<<eb, 256, 0, stream>>>(esrc, edst, cursor, csr, E);

    auto blocksFor = [](int n, int npb) {
        int b = (n + npb - 1) / npb;
        return b < 2048 ? b : 2048;
    };

    float* h1 = bufA;  // [N x 32]
    float* h2 = bufB;  // [N x 64]
    float* h3 = bufA;  // [N x 64]  (h1 dead after L2)
    float* g_ = bufC;  // [N x 32]
    float* h4 = bufB;  // [N x 32]  (h2 dead after fold... after L3; safe: L4 reads g_)

    // L1: raw(3) -> h1(32).  NPB=128.
    k_lvl1<<<blocksFor(N, 128), 512, 0, stream>>>(raw, h1, offsets, csr, inv_cnt, Wa1, We1, N);
    // L2: h1(32) -> h2(64).  NPB=32.
    k_lvl2<<<blocksFor(N, 32), 512, 0, stream>>>(h1, h2, offsets, csr, inv_cnt, Wa2, We2, N);
    // L3: h2(64) -> h3(64).  NPB=16.
    k_lvl3<<<blocksFor(N, 16), 512, 0, stream>>>(h2, h3, offsets, csr, inv_cnt, Wa3, We3, N);
    // fold: g = h3 @ Wa4  (N x 32)
    k_fold<<<(N + 31) / 32, 256, 0, stream>>>(h3, Wa4, g_, N);
    // L4: g(32) -> h4(32), Wa absorbed.  NPB=32.
    k_lvl4<<<blocksFor(N, 32), 512, 0, stream>>>(g_, h4, offsets, csr, inv_cnt, nullptr, We4, N);

    k_out<<<(B + 31) / 32, 256, 0, stream>>>(h4, nodes, Wout, out, B);
}

// Round 9
// 246.046 us; speedup vs baseline: 1.7313x; 1.0241x over previous
//
#include <hip/hip_runtime.h>

// GraphSAGE forward — round 9: round-8 champion level kernels (UNTOUCHED) +
// two-pass bucketed CSR build replacing the 58µs random-atomic scatter.
//
// Hard-won invariants:
//  - Gather reads ONE full contiguous row per vmem instruction, indices
//    shfl-broadcast (r3/r4 fragmentation: FETCH 199-636MB).
//  - Gather stays fused with the level GEMMs at moderate occupancy (r7's
//    dedicated 32-wave gather kernel doubled HBM traffic).
//  - Scattered 4B writes across XCDs cost a 64B HBM line each (r8 k_scatter:
//    54MB writes). Fix: bucket by dst so final csr writes are block-local.
//  - mean_agg(h)@W == mean_agg(h@W) (fold verified r5-r8).

#define BSHIFT 9                    // 512 nodes per bucket
#define MAXBUCK 256                 // supports N <= 131072

__global__ __launch_bounds__(256) void k_count(const int* __restrict__ edst,
                                               int* __restrict__ deg, int E) {
    int t = blockIdx.x * blockDim.x + threadIdx.x;
    if (t < E) atomicAdd(&deg[edst[t]], 1);
}

__global__ __launch_bounds__(256) void k_blocksum(const int* __restrict__ deg,
                                                  int* __restrict__ bsums, int N) {
    __shared__ int s[256];
    int t = threadIdx.x;
    int base = blockIdx.x * 1024 + t * 4;
    int v = 0;
#pragma unroll
    for (int j = 0; j < 4; j++) { int idx = base + j; if (idx < N) v += deg[idx]; }
    s[t] = v; __syncthreads();
    for (int o = 128; o > 0; o >>= 1) { if (t < o) s[t] += s[t + o]; __syncthreads(); }
    if (t == 0) bsums[blockIdx.x] = s[0];
}

__global__ __launch_bounds__(256) void k_scantop(int* __restrict__ bsums, int NB) {
    __shared__ int s[256];
    int t = threadIdx.x;
    int v = (t < NB) ? bsums[t] : 0;
    s[t] = v; __syncthreads();
    for (int o = 1; o < 256; o <<= 1) {
        int x = (t >= o) ? s[t - o] : 0;
        __syncthreads();
        s[t] += x;
        __syncthreads();
    }
    if (t < NB) bsums[t] = s[t] - v;
}

__global__ __launch_bounds__(256) void k_scanfinal(const int* __restrict__ deg,
                                                   const int* __restrict__ bsums,
                                                   int* __restrict__ offsets,
                                                   float* __restrict__ inv_cnt,
                                                   int N, int E) {
    __shared__ int s[256];
    int t = threadIdx.x, b = blockIdx.x;
    int base = b * 1024 + t * 4;
    int d[4]; int lsum = 0;
#pragma unroll
    for (int j = 0; j < 4; j++) { int idx = base + j; d[j] = (idx < N) ? deg[idx] : 0; lsum += d[j]; }
    s[t] = lsum; __syncthreads();
    for (int o = 1; o < 256; o <<= 1) {
        int x = (t >= o) ? s[t - o] : 0;
        __syncthreads();
        s[t] += x;
        __syncthreads();
    }
    int p = bsums[b] + s[t] - lsum;
#pragma unroll
    for (int j = 0; j < 4; j++) {
        int idx = base + j;
        if (idx < N) {
            offsets[idx] = p;
            inv_cnt[idx] = 1.0f / (float)(d[j] > 0 ? d[j] : 1);
            p += d[j];
        }
    }
    if (b == 0 && t == 0) offsets[N] = E;
}

// bcur[b] = offsets[min(b<<BSHIFT, N)]  (bucket staging cursors)
__global__ __launch_bounds__(256) void k_binit(const int* __restrict__ offsets,
                                               int* __restrict__ bcur, int nbuck, int N) {
    int b = blockIdx.x * blockDim.x + threadIdx.x;
    if (b < nbuck) {
        int node = b << BSHIFT;
        bcur[b] = offsets[node < N ? node : N];
    }
}

// Phase A: partition edges into dst-buckets; staged (src,dst) pairs land in
// the bucket's final csr edge range (dense-ish contiguous runs per block).
__global__ __launch_bounds__(512) void k_bucket(const int* __restrict__ esrc,
                                                const int* __restrict__ edst,
                                                int* __restrict__ bcur,
                                                int2* __restrict__ staging,
                                                int nbuck, int E) {
    __shared__ int hist[MAXBUCK];
    __shared__ int bbase[MAXBUCK];
    const int t = threadIdx.x;
    const int e = blockIdx.x * 512 + t;
    int src = 0, dst = 0, b = 0;
    if (e < E) { src = esrc[e]; dst = edst[e]; b = dst >> BSHIFT; }
    for (int i = t; i < nbuck; i += 512) hist[i] = 0;
    __syncthreads();
    int rank = 0;
    if (e < E) rank = atomicAdd(&hist[b], 1);
    __syncthreads();
    for (int i = t; i < nbuck; i += 512)
        bbase[i] = hist[i] ? atomicAdd(&bcur[i], hist[i]) : 0;
    __syncthreads();
    if (e < E) staging[bbase[b] + rank] = make_int2(src, dst);
}

// Phase B: one block per bucket; LDS cursors; csr writes stay inside the
// bucket's contiguous ~35-70KB region (single block/XCD -> line-dense).
__global__ __launch_bounds__(512) void k_place(const int2* __restrict__ staging,
                                               const int* __restrict__ offsets,
                                               int* __restrict__ csr, int N, int E) {
    __shared__ int cur[1 << BSHIFT];
    const int t = threadIdx.x;
    const int nbase = blockIdx.x << BSHIFT;
    const int nend = min(nbase + (1 << BSHIFT), N);
    for (int i = t; i < nend - nbase; i += 512) cur[i] = offsets[nbase + i];
    __syncthreads();
    const int estart = offsets[nbase], eend = offsets[nend];
    for (int e = estart + t; e < eend; e += 512) {
        int2 pr = staging[e];
        int pos = atomicAdd(&cur[pr.y - nbase], 1);
        csr[pos] = pr.x;
    }
}

// ---- round-2/8 proven fused level body (wave-private slots, no inner barriers) ----
template <int DIN, int DMID, int DOUT, int GSIZE, bool HAS_WA>
__device__ __forceinline__ void level_body(
    const float* __restrict__ hprev, float* __restrict__ hnext,
    const int* __restrict__ offsets, const int* __restrict__ csr,
    const float* __restrict__ inv_cnt,
    const float* __restrict__ Wa, const float* __restrict__ We, int N) {
    constexpr int WAVES = 8;
    constexpr int NPG = 64 / GSIZE;   // nodes per wave
    constexpr int NPB = WAVES * NPG;  // nodes per block
    constexpr bool V2 = (DIN == 2 * GSIZE);

    __shared__ float sWa[HAS_WA ? DIN * DMID : 1];
    __shared__ float sWe[DMID * DOUT];
    __shared__ float sM[NPB * DIN];   // wave-private slots
    __shared__ float sA[NPB * DMID];  // wave-private slots

    if constexpr (HAS_WA)
        for (int i = threadIdx.x; i < DIN * DMID; i += 512) sWa[i] = Wa[i];
    for (int i = threadIdx.x; i < DMID * DOUT; i += 512) sWe[i] = We[i];
    __syncthreads();

    const int lane = threadIdx.x & 63;
    const int wid  = threadIdx.x >> 6;
    const int g    = lane / GSIZE;
    const int lg   = lane & (GSIZE - 1);
    const int slot = wid * NPG + g;
    const int srcb = g * GSIZE;
    const long stride = (long)gridDim.x * NPB;

    for (long base = (long)blockIdx.x * NPB; base < N; base += stride) {
        int node = (int)base + slot;
        if (node < N) {
            int start = offsets[node], end = offsets[node + 1];
            float m0 = 0, m1 = 0, n0 = 0, n1 = 0, p0 = 0, p1 = 0, q0 = 0, q1 = 0;
            for (int bb = start; bb < end; bb += GSIZE) {
                int cnt = min(GSIZE, end - bb);
                int sidx = (lg < cnt) ? csr[bb + lg] : 0;
                int i = 0;
                for (; i + 4 <= cnt; i += 4) {
                    int s0 = __shfl(sidx, srcb + i);
                    int s1 = __shfl(sidx, srcb + i + 1);
                    int s2 = __shfl(sidx, srcb + i + 2);
                    int s3 = __shfl(sidx, srcb + i + 3);
                    if (V2) {
                        const float2* hp = (const float2*)hprev;
                        float2 v0 = hp[(size_t)s0 * (DIN / 2) + lg];
                        float2 v1 = hp[(size_t)s1 * (DIN / 2) + lg];
                        float2 v2 = hp[(size_t)s2 * (DIN / 2) + lg];
                        float2 v3 = hp[(size_t)s3 * (DIN / 2) + lg];
                        m0 += v0.x; m1 += v0.y;
                        n0 += v1.x; n1 += v1.y;
                        p0 += v2.x; p1 += v2.y;
                        q0 += v3.x; q1 += v3.y;
                    } else if (lg < DIN) {
                        m0 += hprev[(size_t)s0 * DIN + lg];
                        n0 += hprev[(size_t)s1 * DIN + lg];
                        p0 += hprev[(size_t)s2 * DIN + lg];
                        q0 += hprev[(size_t)s3 * DIN + lg];
                    }
                }
                for (; i < cnt; ++i) {
                    int s0 = __shfl(sidx, srcb + i);
                    if (V2) {
                        const float2* hp = (const float2*)hprev;
                        float2 v0 = hp[(size_t)s0 * (DIN / 2) + lg];
                        m0 += v0.x; m1 += v0.y;
                    } else if (lg < DIN) {
                        m0 += hprev[(size_t)s0 * DIN + lg];
                    }
                }
            }
            float ic = inv_cnt[node];
            float fx = ((m0 + n0) + (p0 + q0)) * ic;
            if (V2) {
                float fy = ((m1 + n1) + (p1 + q1)) * ic;
                sM[slot * DIN + 2 * lg]     = fx;
                sM[slot * DIN + 2 * lg + 1] = fy;
            } else if (lg < DIN) {
                sM[slot * DIN + lg] = fx;
            }
        }
        // a = relu(m @ Wa)  (or a = relu(m) when Wa is folded upstream)
        constexpr int AO = NPG * DMID;
#pragma unroll
        for (int r = 0; r < AO / 64; ++r) {
            int oi = r * 64 + lane;
            int sl = wid * NPG + oi / DMID;
            int col = oi & (DMID - 1);
            if ((int)base + sl < N) {
                if constexpr (HAS_WA) {
                    float v = 0.f;
#pragma unroll
                    for (int k = 0; k < DIN; ++k) v += sM[sl * DIN + k] * sWa[k * DMID + col];
                    sA[sl * DMID + col] = fmaxf(v, 0.f);
                } else {
                    sA[sl * DMID + col] = fmaxf(sM[sl * DIN + col], 0.f);
                }
            }
        }
        // h = relu(a @ We)
        constexpr int HO = NPG * DOUT;
#pragma unroll
        for (int r = 0; r < HO / 64; ++r) {
            int oi = r * 64 + lane;
            int sl = wid * NPG + oi / DOUT;
            int col = oi & (DOUT - 1);
            int nd = (int)base + sl;
            if (nd < N) {
                float v = 0.f;
#pragma unroll
                for (int k = 0; k < DMID; ++k) v += sA[sl * DMID + k] * sWe[k * DOUT + col];
                hnext[(size_t)nd * DOUT + col] = fmaxf(v, 0.f);
            }
        }
    }
}

// Distinctly-named wrappers for clean rocprof attribution.
__global__ __launch_bounds__(512, 8) void k_lvl1(
    const float* __restrict__ hprev, float* __restrict__ hnext,
    const int* __restrict__ offsets, const int* __restrict__ csr,
    const float* __restrict__ inv_cnt, const float* __restrict__ Wa,
    const float* __restrict__ We, int N) {
    level_body<3, 32, 32, 4, true>(hprev, hnext, offsets, csr, inv_cnt, Wa, We, N);
}
__global__ __launch_bounds__(512, 8) void k_lvl2(
    const float* __restrict__ hprev, float* __restrict__ hnext,
    const int* __restrict__ offsets, const int* __restrict__ csr,
    const float* __restrict__ inv_cnt, const float* __restrict__ Wa,
    const float* __restrict__ We, int N) {
    level_body<32, 32, 64, 16, true>(hprev, hnext, offsets, csr, inv_cnt, Wa, We, N);
}
__global__ __launch_bounds__(512, 8) void k_lvl3(
    const float* __restrict__ hprev, float* __restrict__ hnext,
    const int* __restrict__ offsets, const int* __restrict__ csr,
    const float* __restrict__ inv_cnt, const float* __restrict__ Wa,
    const float* __restrict__ We, int N) {
    level_body<64, 64, 64, 32, true>(hprev, hnext, offsets, csr, inv_cnt, Wa, We, N);
}
__global__ __launch_bounds__(512, 8) void k_lvl4(
    const float* __restrict__ hprev, float* __restrict__ hnext,
    const int* __restrict__ offsets, const int* __restrict__ csr,
    const float* __restrict__ inv_cnt, const float* __restrict__ Wa,
    const float* __restrict__ We, int N) {
    level_body<32, 32, 32, 16, false>(hprev, hnext, offsets, csr, inv_cnt, Wa, We, N);
}

// Dense fold: g[N x 32] = h3[N x 64] @ Wa4[64 x 32]  (no relu).
__global__ __launch_bounds__(256) void k_fold(const float* __restrict__ h3,
                                              const float* __restrict__ Wg,
                                              float* __restrict__ g, int N) {
    __shared__ float sW[64 * 32];
    __shared__ float sH[32 * 68];
    const int t = threadIdx.x;
    const int base = blockIdx.x * 32;
    for (int i = t; i < 64 * 32; i += 256) sW[i] = Wg[i];
    for (int idx = t; idx < 512; idx += 256) {
        int row = idx >> 4, q = idx & 15;
        int node = base + row;
        float4 v = (node < N) ? ((const float4*)h3)[(size_t)node * 16 + q]
                              : make_float4(0.f, 0.f, 0.f, 0.f);
        *(float4*)&sH[row * 68 + 4 * q] = v;
    }
    __syncthreads();
    const int row = t >> 3, q = t & 7;
    const int node = base + row;
    if (node < N) {
        float ax = 0.f, ay = 0.f, az = 0.f, aw = 0.f;
#pragma unroll
        for (int k = 0; k < 64; ++k) {
            float mv = sH[row * 68 + k];
            const float* w = &sW[k * 32 + 4 * q];
            ax += mv * w[0]; ay += mv * w[1]; az += mv * w[2]; aw += mv * w[3];
        }
        float4 r = make_float4(ax, ay, az, aw);
        ((float4*)g)[(size_t)node * 8 + q] = r;
    }
}

// Staged output projection: rows via LDS, cooperative 40-col outputs.
__global__ __launch_bounds__(256, 8) void k_out(const float* __restrict__ h,
                                                const int* __restrict__ nodes,
                                                const float* __restrict__ Wout,
                                                float* __restrict__ out, int B) {
    __shared__ alignas(16) float sH[32][36];
    __shared__ float sW[32 * 40];
    __shared__ int sIdx[32];
    const int t = threadIdx.x;
    const int base = blockIdx.x * 32;
    if (t < 32) sIdx[t] = (base + t < B) ? nodes[base + t] : 0;
    for (int i = t; i < 32 * 40; i += 256) sW[i] = Wout[i];
    __syncthreads();
    {
        int g = t >> 3, lg = t & 7;
        *(float4*)&sH[g][4 * lg] = ((const float4*)h)[(size_t)sIdx[g] * 8 + lg];
    }
    __syncthreads();
#pragma unroll
    for (int j = 0; j < 5; ++j) {
        int idx = t + j * 256;  // 32*40 = 1280 outputs
        int n = idx / 40, c = idx % 40;
        if (base + n < B) {
            float s = 0.f;
#pragma unroll
            for (int k = 0; k < 32; ++k) s += sH[n][k] * sW[k * 40 + c];
            out[(size_t)(base + n) * 40 + c] = s;
        }
    }
}

extern "C" void kernel_launch(void* const* d_in, const int* in_sizes, int n_in,
                              void* d_out, int out_size, void* d_ws, size_t ws_size,
                              hipStream_t stream) {
    const float* raw  = (const float*)d_in[0];
    const int* nodes  = (const int*)d_in[1];
    const int* esrc   = (const int*)d_in[2];
    const int* edst   = (const int*)d_in[3];
    const float* Wa1 = (const float*)d_in[4];
    const float* Wa2 = (const float*)d_in[5];
    const float* Wa3 = (const float*)d_in[6];
    const float* Wa4 = (const float*)d_in[7];
    const float* We1 = (const float*)d_in[8];
    const float* We2 = (const float*)d_in[9];
    const float* We3 = (const float*)d_in[10];
    const float* We4 = (const float*)d_in[11];
    const float* Wout = (const float*)d_in[12];
    float* out = (float*)d_out;

    int N = in_sizes[1];   // 50000
    int E = in_sizes[2];   // 850000
    int B = N;
    int nbuck = (N + (1 << BSHIFT) - 1) >> BSHIFT;   // 98

    char* p = (char*)d_ws;
    auto alloc = [&](size_t bytes) -> char* {
        char* r = p;
        p += (bytes + 255) & ~(size_t)255;
        return r;
    };
    int*   deg     = (int*)alloc((size_t)N * 4);
    int*   offsets = (int*)alloc((size_t)(N + 1) * 4);
    float* inv_cnt = (float*)alloc((size_t)N * 4);
    int NB = (N + 1023) / 1024;
    int*   bsums   = (int*)alloc((size_t)NB * 4);
    int*   bcur    = (int*)alloc((size_t)MAXBUCK * 4);
    int*   csr     = (int*)alloc((size_t)E * 4);
    float* bufA    = (float*)alloc((size_t)N * 64 * 4);   // staging overlay + h1/h3
    float* bufB    = (float*)alloc((size_t)N * 64 * 4);
    float* bufC    = (float*)alloc((size_t)N * 32 * 4);
    (void)ws_size; (void)n_in; (void)out_size;

    int2* staging = (int2*)bufA;   // 6.8MB, dead before k_lvl1 writes h1

    hipMemsetAsync(deg, 0, (size_t)N * 4, stream);
    int eb256 = (E + 255) / 256;
    int eb512 = (E + 511) / 512;
    k_count<<<eb256, 256, 0, stream>>>(edst, deg, E);
    k_blocksum<<<NB, 256, 0, stream>>>(deg, bsums, N);
    k_scantop<<<1, 256, 0, stream>>>(bsums, NB);
    k_scanfinal<<<NB, 256, 0, stream>>>(deg, bsums, offsets, inv_cnt, N, E);
    k_binit<<<(nbuck + 255) / 256, 256, 0, stream>>>(offsets, bcur, nbuck, N);
    k_bucket<<<eb512, 512, 0, stream>>>(esrc, edst, bcur, staging, nbuck, E);
    k_place<<<nbuck, 512, 0, stream>>>(staging, offsets, csr, N, E);

    auto blocksFor = [](int n, int npb) {
        int b = (n + npb - 1) / npb;
        return b < 2048 ? b : 2048;
    };

    float* h1 = bufA;  // [N x 32]
    float* h2 = bufB;  // [N x 64]
    float* h3 = bufA;  // [N x 64]  (h1 dead after L2)
    float* g_ = bufC;  // [N x 32]
    float* h4 = bufB;  // [N x 32]  (h2 dead after L3)

    // L1: raw(3) -> h1(32).  NPB=128.
    k_lvl1<<<blocksFor(N, 128), 512, 0, stream>>>(raw, h1, offsets, csr, inv_cnt, Wa1, We1, N);
    // L2: h1(32) -> h2(64).  NPB=32.
    k_lvl2<<<blocksFor(N, 32), 512, 0, stream>>>(h1, h2, offsets, csr, inv_cnt, Wa2, We2, N);
    // L3: h2(64) -> h3(64).  NPB=16.
    k_lvl3<<<blocksFor(N, 16), 512, 0, stream>>>(h2, h3, offsets, csr, inv_cnt, Wa3, We3, N);
    // fold: g = h3 @ Wa4  (N x 32)
    k_fold<<<(N + 31) / 32, 256, 0, stream>>>(h3, Wa4, g_, N);
    // L4: g(32) -> h4(32), Wa absorbed.  NPB=32.
    k_lvl4<<<blocksFor(N, 32), 512, 0, stream>>>(g_, h4, offsets, csr, inv_cnt, nullptr, We4, N);

    k_out<<<(B + 31) / 32, 256, 0, stream>>>(h4, nodes, Wout, out, B);
}